// Round 5
// baseline (805.057 us; speedup 1.0000x reference)
//
#include <hip/hip_runtime.h>
#include <cstdint>
#include <cstddef>

#define H_DIM 2048
#define I_DIM 1024
#define E_NUM 16
#define T_NUM 2048
#define BK 64

typedef float floatx4 __attribute__((ext_vector_type(4)));
using short8 = __attribute__((ext_vector_type(8))) short;

__device__ __forceinline__ short f2bf(float f) {
  unsigned u = __float_as_uint(f);
  u += 0x7FFFu + ((u >> 16) & 1u);
  return (short)(u >> 16);
}

// async global->LDS, 16B per lane. LDS dest must be wave-uniform base + lane*16.
__device__ __forceinline__ void cp16(const void* g, void* l) {
  __builtin_amdgcn_global_load_lds(
      (__attribute__((address_space(1))) void*)(void*)g,
      (__attribute__((address_space(3))) void*)l, 16, 0, 0);
}

// ---------------- plain transpose + fp32->bf16: in[e][R][C] -> out[e][C][R] ----------------
// LDS-free: each lane transposes an 8x8 subtile in registers. 128x128 tile per block.
__global__ __launch_bounds__(256) void transpose_bf16_kernel(
    const float* __restrict__ inA, const float* __restrict__ inB,
    short* __restrict__ outA, short* __restrict__ outB, int R, int C, int zsplit) {
  int z = blockIdx.z;
  const float* in = (z < zsplit) ? inA : inB;
  short* out = (z < zsplit) ? outA : outB;
  int e = (z < zsplit) ? z : z - zsplit;
  int r0 = blockIdx.y * 128, c0 = blockIdx.x * 128;
  int tid = threadIdx.x;
  int sr = (((tid >> 3) & 7) << 3) + (((tid >> 6) & 1) << 6);
  int sc = ((tid & 7) << 3) + ((tid >> 7) << 6);
  const float* src = in + ((size_t)e * R + r0 + sr) * C + c0 + sc;
  short* dst = out + ((size_t)e * C + c0 + sc) * R + r0 + sr;
  float fr[8][8];
#pragma unroll
  for (int i = 0; i < 8; ++i) {
    float4 a = *(const float4*)(src + (size_t)i * C);
    float4 b = *(const float4*)(src + (size_t)i * C + 4);
    fr[i][0] = a.x; fr[i][1] = a.y; fr[i][2] = a.z; fr[i][3] = a.w;
    fr[i][4] = b.x; fr[i][5] = b.y; fr[i][6] = b.z; fr[i][7] = b.w;
  }
#pragma unroll
  for (int c = 0; c < 8; ++c) {
    short8 s;
#pragma unroll
    for (int j = 0; j < 8; ++j) s[j] = f2bf(fr[j][c]);
    *(short8*)(dst + (size_t)c * R) = s;
  }
}

// ---------------- gate/up merge-transpose: wguT[e][c'][h], c' interleaves 16-col groups ----
// c' in [0,2048): matrix = (c'>>4)&1 (0=gate,1=up), source I-col = (c'>>5)*16 + (c'&15).
__global__ __launch_bounds__(256) void transpose_gu_kernel(
    const float* __restrict__ wg, const float* __restrict__ wu,
    short* __restrict__ wguT) {
  int e = blockIdx.z;
  int r0 = blockIdx.y * 128, c0 = blockIdx.x * 128;  // r = h, c = merged c'
  int tid = threadIdx.x;
  int sr = (((tid >> 3) & 7) << 3) + (((tid >> 6) & 1) << 6);
  int sc = ((tid & 7) << 3) + ((tid >> 7) << 6);
  int cg = c0 + sc;  // 8 consecutive output rows cg..cg+7: same matrix, consecutive icol
  const float* in = ((cg >> 4) & 1) ? wu : wg;
  int icol = ((cg >> 5) << 4) + (cg & 15);
  const float* src = in + ((size_t)e * H_DIM + r0 + sr) * I_DIM + icol;
  short* dst = wguT + ((size_t)e * 2048 + cg) * H_DIM + r0 + sr;
  float fr[8][8];
#pragma unroll
  for (int i = 0; i < 8; ++i) {
    float4 a = *(const float4*)(src + (size_t)i * I_DIM);
    float4 b = *(const float4*)(src + (size_t)i * I_DIM + 4);
    fr[i][0] = a.x; fr[i][1] = a.y; fr[i][2] = a.z; fr[i][3] = a.w;
    fr[i][4] = b.x; fr[i][5] = b.y; fr[i][6] = b.z; fr[i][7] = b.w;
  }
#pragma unroll
  for (int c = 0; c < 8; ++c) {
    short8 s;
#pragma unroll
    for (int j = 0; j < 8; ++j) s[j] = f2bf(fr[j][c]);
    *(short8*)(dst + (size_t)c * H_DIM) = s;
  }
}

// ---------------- router ----------------
__global__ __launch_bounds__(256) void router_kernel(
    const float* __restrict__ x, const float* __restrict__ wr,
    short* __restrict__ xbf, int* __restrict__ counts,
    int* __restrict__ tokl, float* __restrict__ wgtl) {
  int t = blockIdx.x;
  int tid = threadIdx.x;
  const float* xr = x + (size_t)t * H_DIM;
  float acc[E_NUM];
#pragma unroll
  for (int e = 0; e < 16; ++e) acc[e] = 0.f;
  for (int h = tid; h < H_DIM; h += 256) {
    float xv = xr[h];
    xbf[(size_t)t * H_DIM + h] = f2bf(xv);
    const float4* w4 = (const float4*)(wr + h * 16);
#pragma unroll
    for (int j = 0; j < 4; ++j) {
      float4 wv = w4[j];
      acc[j * 4 + 0] += xv * wv.x;
      acc[j * 4 + 1] += xv * wv.y;
      acc[j * 4 + 2] += xv * wv.z;
      acc[j * 4 + 3] += xv * wv.w;
    }
  }
#pragma unroll
  for (int off = 32; off >= 1; off >>= 1)
#pragma unroll
    for (int e = 0; e < 16; ++e) acc[e] += __shfl_down(acc[e], off);
  __shared__ float red[4][16];
  int wv_ = tid >> 6, ln = tid & 63;
  if (ln == 0)
#pragma unroll
    for (int e = 0; e < 16; ++e) red[wv_][e] = acc[e];
  __syncthreads();
  if (tid < 64) {
    float logit = -1e30f;
    if (ln < 16) logit = red[0][ln] + red[1][ln] + red[2][ln] + red[3][ln];
    float m = logit;
#pragma unroll
    for (int off = 8; off >= 1; off >>= 1) m = fmaxf(m, __shfl_xor(m, off));
    float p = __expf(logit - m);
    float myp = p;
    float bestv[4]; int besti[4];
#pragma unroll
    for (int kk = 0; kk < 4; ++kk) {
      float cv = myp; int ci = ln;
#pragma unroll
      for (int off = 8; off >= 1; off >>= 1) {
        float ov = __shfl_xor(cv, off);
        int oi = __shfl_xor(ci, off);
        if (ov > cv || (ov == cv && oi < ci)) { cv = ov; ci = oi; }
      }
      bestv[kk] = cv; besti[kk] = ci;
      if (ln == ci) myp = -1.f;
    }
    float s4 = bestv[0] + bestv[1] + bestv[2] + bestv[3];
    if (ln < 4) {
      int e = besti[ln];
      int slot = atomicAdd(&counts[e], 1);
      tokl[e * T_NUM + slot] = t * 4 + ln;
      wgtl[e * T_NUM + slot] = bestv[ln] / s4;
    }
  }
}

// ---------------- tile scheduler: dense (e, mtile) list (one wave, parallel) ----------------
__global__ void sched_kernel(const int* __restrict__ counts, int* __restrict__ desc,
                             int* __restrict__ ntiles) {
  int ln = threadIdx.x;  // 64 threads, 1 block
  int nt = (ln < E_NUM) ? ((counts[ln] + 127) >> 7) : 0;
  int base = 0, tot = 0;
#pragma unroll
  for (int j = 0; j < E_NUM; ++j) {
    int v = __shfl(nt, j);
    if (j < ln) base += v;
    tot += v;
  }
  if (ln < E_NUM)
    for (int m = 0; m < nt; ++m) desc[base + m] = ln | (m << 8);
  if (ln == 0) ntiles[0] = tot;
}

// ---------------- merged gate+up GEMM (single B = wguT, N=2048) + SwiGLU epilogue --------
// 33 KB LDS, 1024 jobs, grid 1024 -> 4 blocks/CU. b-frags j=2p/2p+1 are (gate,up)
// for the SAME I-columns thanks to the interleaved wguT layout.
__global__ __launch_bounds__(256, 4) void gateup_kernel(
    const short* __restrict__ xbf, const short* __restrict__ wguT,
    const int* __restrict__ counts, const int* __restrict__ tokl,
    const float* __restrict__ wgtl, const int* __restrict__ desc,
    const int* __restrict__ ntiles, short* __restrict__ act) {
  __shared__ short Al[128 * BK];
  __shared__ short Bl[128 * BK];
  __shared__ int s_tok[128];
  __shared__ float s_w[128];
  int tid = threadIdx.x;
  int wv = tid >> 6, ln = tid & 63;
  int msub = (wv & 1) * 64, nsub = (wv >> 1) * 64;
  int lm = ln & 15, kq = ln >> 4;
  int total = ntiles[0] * 16;
  for (int w = blockIdx.x; w < total; w += gridDim.x) {
    int nt = w & 15;
    int d = desc[w >> 4];
    int e = d & 0xFF, m0 = (d >> 8) * 128, n0 = nt * 128;
    int cnt = counts[e];
    __syncthreads();  // protect s_tok/s_w from previous tile's epilogue
    if (tid < 128) {
      int idx = m0 + tid;
      int ok = idx < cnt;
      s_tok[tid] = ok ? tokl[e * T_NUM + idx] : 0;
      s_w[tid] = ok ? wgtl[e * T_NUM + idx] : 0.f;
    }
    __syncthreads();
    const short* ab[4]; const short* bb[4];
#pragma unroll
    for (int q = 0; q < 4; ++q) {
      int f = q * 256 + tid;
      int row = f >> 3;
      int c = (f & 7) ^ (row & 7);
      ab[q] = xbf + (size_t)(s_tok[row] >> 2) * H_DIM + c * 8;
      bb[q] = wguT + ((size_t)e * 2048 + n0 + row) * H_DIM + c * 8;
    }
    floatx4 acc[16];
    floatx4 zero = {0.f, 0.f, 0.f, 0.f};
#pragma unroll
    for (int i = 0; i < 16; ++i) acc[i] = zero;
    for (int k0 = 0; k0 < H_DIM; k0 += BK) {
      __syncthreads();
#pragma unroll
      for (int q = 0; q < 4; ++q) {
        int l8 = (q * 256 + tid) * 8;
        cp16(ab[q] + k0, Al + l8);
        cp16(bb[q] + k0, Bl + l8);
      }
      __syncthreads();
#pragma unroll
      for (int s = 0; s < 2; ++s) {
        int posA = ((s * 4 + kq) ^ (lm & 7)) * 8;
        short8 a[4], b[4];
#pragma unroll
        for (int i = 0; i < 4; ++i) a[i] = *(const short8*)(Al + (msub + i * 16 + lm) * BK + posA);
#pragma unroll
        for (int j = 0; j < 4; ++j) b[j] = *(const short8*)(Bl + (nsub + j * 16 + lm) * BK + posA);
#pragma unroll
        for (int i = 0; i < 4; ++i)
#pragma unroll
          for (int j = 0; j < 4; ++j)
            acc[i * 4 + j] = __builtin_amdgcn_mfma_f32_16x16x32_bf16(a[i], b[j], acc[i * 4 + j], 0, 0, 0);
      }
    }
    int crem = cnt - m0;
#pragma unroll
    for (int i = 0; i < 4; ++i)
#pragma unroll
      for (int p = 0; p < 2; ++p) {
        floatx4 g = acc[i * 4 + 2 * p];
        floatx4 u = acc[i * 4 + 2 * p + 1];
        int col = ((n0 + nsub) >> 1) + p * 16 + lm;  // I-column
#pragma unroll
        for (int r = 0; r < 4; ++r) {
          int rl = msub + i * 16 + kq * 4 + r;
          if (rl < crem) {
            float gv = g[r];
            float av = gv / (1.f + __expf(-gv)) * u[r] * s_w[rl];
            act[(size_t)s_tok[rl] * I_DIM + col] = f2bf(av);
          }
        }
      }
  }
}

// ---------------- down GEMM -> per-slot fp32 buffer (no atomics) ----------------
// 33 KB LDS, grid 1024 -> 4 blocks/CU.
__global__ __launch_bounds__(256, 4) void down_kernel(
    const short* __restrict__ act, const short* __restrict__ wdT,
    const int* __restrict__ counts, const int* __restrict__ tokl,
    const int* __restrict__ desc, const int* __restrict__ ntiles,
    float* __restrict__ outS) {
  __shared__ short Al[128 * BK];
  __shared__ short Bl[128 * BK];
  __shared__ int s_tok[128];
  int tid = threadIdx.x;
  int wv = tid >> 6, ln = tid & 63;
  int msub = (wv & 1) * 64, nsub = (wv >> 1) * 64;
  int lm = ln & 15, kq = ln >> 4;
  int total = ntiles[0] * 16;
  for (int w = blockIdx.x; w < total; w += gridDim.x) {
    int nt = w & 15;
    int d = desc[w >> 4];
    int e = d & 0xFF, m0 = (d >> 8) * 128, n0 = nt * 128;
    int cnt = counts[e];
    __syncthreads();
    if (tid < 128) {
      int idx = m0 + tid;
      s_tok[tid] = (idx < cnt) ? tokl[e * T_NUM + idx] : 0;
    }
    __syncthreads();
    const short* ab[4]; const short* bb[4];
#pragma unroll
    for (int q = 0; q < 4; ++q) {
      int f = q * 256 + tid;
      int row = f >> 3;
      int c = (f & 7) ^ (row & 7);
      ab[q] = act + (size_t)s_tok[row] * I_DIM + c * 8;
      bb[q] = wdT + ((size_t)e * H_DIM + n0 + row) * I_DIM + c * 8;
    }
    floatx4 acc[16];
    floatx4 zero = {0.f, 0.f, 0.f, 0.f};
#pragma unroll
    for (int i = 0; i < 16; ++i) acc[i] = zero;
    for (int k0 = 0; k0 < I_DIM; k0 += BK) {
      __syncthreads();
#pragma unroll
      for (int q = 0; q < 4; ++q) {
        int l8 = (q * 256 + tid) * 8;
        cp16(ab[q] + k0, Al + l8);
        cp16(bb[q] + k0, Bl + l8);
      }
      __syncthreads();
#pragma unroll
      for (int s = 0; s < 2; ++s) {
        int posA = ((s * 4 + kq) ^ (lm & 7)) * 8;
        short8 a[4], b[4];
#pragma unroll
        for (int i = 0; i < 4; ++i) a[i] = *(const short8*)(Al + (msub + i * 16 + lm) * BK + posA);
#pragma unroll
        for (int j = 0; j < 4; ++j) b[j] = *(const short8*)(Bl + (nsub + j * 16 + lm) * BK + posA);
#pragma unroll
        for (int i = 0; i < 4; ++i)
#pragma unroll
          for (int j = 0; j < 4; ++j)
            acc[i * 4 + j] = __builtin_amdgcn_mfma_f32_16x16x32_bf16(a[i], b[j], acc[i * 4 + j], 0, 0, 0);
      }
    }
    int crem = cnt - m0;
#pragma unroll
    for (int i = 0; i < 4; ++i)
#pragma unroll
      for (int j = 0; j < 4; ++j) {
        int col = n0 + nsub + j * 16 + lm;
#pragma unroll
        for (int r = 0; r < 4; ++r) {
          int rl = msub + i * 16 + kq * 4 + r;
          if (rl < crem) {
            // each (token, slot) row is written by exactly one expert tile: plain store
            outS[(size_t)s_tok[rl] * H_DIM + col] = acc[i * 4 + j][r];
          }
        }
      }
  }
}

// ---------------- slot combine: out[t][h] = sum_{s<4} outS[t*4+s][h] ----------------
__global__ __launch_bounds__(256) void reduce_kernel(
    const float* __restrict__ outS, float* __restrict__ out) {
  const int h4 = H_DIM / 4;  // 512 float4 per row
  const int n = T_NUM * h4;
  for (int i = blockIdx.x * 256 + threadIdx.x; i < n; i += gridDim.x * 256) {
    int t = i >> 9;
    int c = i & (h4 - 1);
    const float4* base = (const float4*)outS + ((size_t)t * 4) * h4 + c;
    float4 a = base[0];
    float4 b = base[h4];
    float4 d = base[2 * h4];
    float4 e = base[3 * h4];
    float4 r;
    r.x = a.x + b.x + d.x + e.x;
    r.y = a.y + b.y + d.y + e.y;
    r.z = a.z + b.z + d.z + e.z;
    r.w = a.w + b.w + d.w + e.w;
    ((float4*)out)[i] = r;
  }
}

extern "C" void kernel_launch(void* const* d_in, const int* in_sizes, int n_in,
                              void* d_out, int out_size, void* d_ws, size_t ws_size,
                              hipStream_t stream) {
  const float* x  = (const float*)d_in[0];
  const float* wr = (const float*)d_in[1];
  const float* wg = (const float*)d_in[2];
  const float* wu = (const float*)d_in[3];
  const float* wd = (const float*)d_in[4];
  float* out = (float*)d_out;

  char* ws = (char*)d_ws;
  const size_t WT_SZ = (size_t)E_NUM * I_DIM * H_DIM * 2;
  size_t off = 0;
  short* wguT = (short*)(ws + off); off += 2 * WT_SZ;  // merged, interleaved gate/up
  short* wdT = (short*)(ws + off); off += WT_SZ;
  short* xbf = (short*)(ws + off); off += (size_t)T_NUM * H_DIM * 2;
  short* act = (short*)(ws + off); off += (size_t)T_NUM * 4 * I_DIM * 2;
  int* counts = (int*)(ws + off); off += 256;
  int* tokl = (int*)(ws + off); off += (size_t)E_NUM * T_NUM * 4;
  float* wgtl = (float*)(ws + off); off += (size_t)E_NUM * T_NUM * 4;
  int* desc = (int*)(ws + off); off += 256 * 4;
  int* ntiles = (int*)(ws + off); off += 64;

  // outS (T*4 x H fp32 = 67.1 MB) aliases wguT (134 MB): dead after gateup (stream-ordered).
  float* outS = (float*)wguT;

  hipMemsetAsync(d_out, 0, (size_t)out_size * sizeof(float), stream);  // router_logits must be 0
  if (off > ws_size) return;
  hipMemsetAsync(counts, 0, 256, stream);

  dim3 blk(256);
  // wgu merge-transpose: out rows c' = 2048, cols h = 2048
  transpose_gu_kernel<<<dim3(2048 / 128, H_DIM / 128, E_NUM), blk, 0, stream>>>(wg, wu, wguT);
  // wd plain transpose: in[e][I][H] -> out[e][H][I]
  transpose_bf16_kernel<<<dim3(H_DIM / 128, I_DIM / 128, E_NUM), blk, 0, stream>>>(
      wd, wd, wdT, wdT, I_DIM, H_DIM, E_NUM);
  router_kernel<<<dim3(T_NUM), blk, 0, stream>>>(x, wr, xbf, counts, tokl, wgtl);
  sched_kernel<<<dim3(1), dim3(64), 0, stream>>>(counts, desc, ntiles);
  gateup_kernel<<<dim3(1024), blk, 0, stream>>>(xbf, wguT, counts, tokl, wgtl, desc, ntiles, act);
  down_kernel<<<dim3(1024), blk, 0, stream>>>(act, wdT, counts, tokl, desc, ntiles, outS);
  reduce_kernel<<<dim3(2048), blk, 0, stream>>>(outS, out);
}

// Round 6
// 629.199 us; speedup vs baseline: 1.2795x; 1.2795x over previous
//
#include <hip/hip_runtime.h>
#include <cstdint>
#include <cstddef>

#define H_DIM 2048
#define I_DIM 1024
#define E_NUM 16
#define T_NUM 2048
#define BK 64

typedef float floatx4 __attribute__((ext_vector_type(4)));
using short8 = __attribute__((ext_vector_type(8))) short;

__device__ __forceinline__ short f2bf(float f) {
  unsigned u = __float_as_uint(f);
  u += 0x7FFFu + ((u >> 16) & 1u);
  return (short)(u >> 16);
}

// async global->LDS, 16B per lane. LDS dest must be wave-uniform base + lane*16.
__device__ __forceinline__ void cp16(const void* g, void* l) {
  __builtin_amdgcn_global_load_lds(
      (__attribute__((address_space(1))) void*)(void*)g,
      (__attribute__((address_space(3))) void*)l, 16, 0, 0);
}

// ---------------- plain transpose + fp32->bf16: in[e][R][C] -> out[e][C][R] ----------------
// LDS-free: each lane transposes an 8x8 subtile in registers. 128x128 tile per block.
__global__ __launch_bounds__(256) void transpose_bf16_kernel(
    const float* __restrict__ inA, const float* __restrict__ inB,
    short* __restrict__ outA, short* __restrict__ outB, int R, int C, int zsplit) {
  int z = blockIdx.z;
  const float* in = (z < zsplit) ? inA : inB;
  short* out = (z < zsplit) ? outA : outB;
  int e = (z < zsplit) ? z : z - zsplit;
  int r0 = blockIdx.y * 128, c0 = blockIdx.x * 128;
  int tid = threadIdx.x;
  int sr = (((tid >> 3) & 7) << 3) + (((tid >> 6) & 1) << 6);
  int sc = ((tid & 7) << 3) + ((tid >> 7) << 6);
  const float* src = in + ((size_t)e * R + r0 + sr) * C + c0 + sc;
  short* dst = out + ((size_t)e * C + c0 + sc) * R + r0 + sr;
  float fr[8][8];
#pragma unroll
  for (int i = 0; i < 8; ++i) {
    float4 a = *(const float4*)(src + (size_t)i * C);
    float4 b = *(const float4*)(src + (size_t)i * C + 4);
    fr[i][0] = a.x; fr[i][1] = a.y; fr[i][2] = a.z; fr[i][3] = a.w;
    fr[i][4] = b.x; fr[i][5] = b.y; fr[i][6] = b.z; fr[i][7] = b.w;
  }
#pragma unroll
  for (int c = 0; c < 8; ++c) {
    short8 s;
#pragma unroll
    for (int j = 0; j < 8; ++j) s[j] = f2bf(fr[j][c]);
    *(short8*)(dst + (size_t)c * R) = s;
  }
}

// ---------------- gate/up merge-transpose: wguT[e][c'][h], c' interleaves 16-col groups ----
// c' in [0,2048): matrix = (c'>>4)&1 (0=gate,1=up), source I-col = (c'>>5)*16 + (c'&15).
__global__ __launch_bounds__(256) void transpose_gu_kernel(
    const float* __restrict__ wg, const float* __restrict__ wu,
    short* __restrict__ wguT) {
  int e = blockIdx.z;
  int r0 = blockIdx.y * 128, c0 = blockIdx.x * 128;  // r = h, c = merged c'
  int tid = threadIdx.x;
  int sr = (((tid >> 3) & 7) << 3) + (((tid >> 6) & 1) << 6);
  int sc = ((tid & 7) << 3) + ((tid >> 7) << 6);
  int cg = c0 + sc;  // 8 consecutive output rows cg..cg+7: same matrix, consecutive icol
  const float* in = ((cg >> 4) & 1) ? wu : wg;
  int icol = ((cg >> 5) << 4) + (cg & 15);
  const float* src = in + ((size_t)e * H_DIM + r0 + sr) * I_DIM + icol;
  short* dst = wguT + ((size_t)e * 2048 + cg) * H_DIM + r0 + sr;
  float fr[8][8];
#pragma unroll
  for (int i = 0; i < 8; ++i) {
    float4 a = *(const float4*)(src + (size_t)i * I_DIM);
    float4 b = *(const float4*)(src + (size_t)i * I_DIM + 4);
    fr[i][0] = a.x; fr[i][1] = a.y; fr[i][2] = a.z; fr[i][3] = a.w;
    fr[i][4] = b.x; fr[i][5] = b.y; fr[i][6] = b.z; fr[i][7] = b.w;
  }
#pragma unroll
  for (int c = 0; c < 8; ++c) {
    short8 s;
#pragma unroll
    for (int j = 0; j < 8; ++j) s[j] = f2bf(fr[j][c]);
    *(short8*)(dst + (size_t)c * H_DIM) = s;
  }
}

// ---------------- router ----------------
__global__ __launch_bounds__(256) void router_kernel(
    const float* __restrict__ x, const float* __restrict__ wr,
    short* __restrict__ xbf, int* __restrict__ counts,
    int* __restrict__ tokl, float* __restrict__ wgtl) {
  int t = blockIdx.x;
  int tid = threadIdx.x;
  const float* xr = x + (size_t)t * H_DIM;
  float acc[E_NUM];
#pragma unroll
  for (int e = 0; e < 16; ++e) acc[e] = 0.f;
  for (int h = tid; h < H_DIM; h += 256) {
    float xv = xr[h];
    xbf[(size_t)t * H_DIM + h] = f2bf(xv);
    const float4* w4 = (const float4*)(wr + h * 16);
#pragma unroll
    for (int j = 0; j < 4; ++j) {
      float4 wv = w4[j];
      acc[j * 4 + 0] += xv * wv.x;
      acc[j * 4 + 1] += xv * wv.y;
      acc[j * 4 + 2] += xv * wv.z;
      acc[j * 4 + 3] += xv * wv.w;
    }
  }
#pragma unroll
  for (int off = 32; off >= 1; off >>= 1)
#pragma unroll
    for (int e = 0; e < 16; ++e) acc[e] += __shfl_down(acc[e], off);
  __shared__ float red[4][16];
  int wv_ = tid >> 6, ln = tid & 63;
  if (ln == 0)
#pragma unroll
    for (int e = 0; e < 16; ++e) red[wv_][e] = acc[e];
  __syncthreads();
  if (tid < 64) {
    float logit = -1e30f;
    if (ln < 16) logit = red[0][ln] + red[1][ln] + red[2][ln] + red[3][ln];
    float m = logit;
#pragma unroll
    for (int off = 8; off >= 1; off >>= 1) m = fmaxf(m, __shfl_xor(m, off));
    float p = __expf(logit - m);
    float myp = p;
    float bestv[4]; int besti[4];
#pragma unroll
    for (int kk = 0; kk < 4; ++kk) {
      float cv = myp; int ci = ln;
#pragma unroll
      for (int off = 8; off >= 1; off >>= 1) {
        float ov = __shfl_xor(cv, off);
        int oi = __shfl_xor(ci, off);
        if (ov > cv || (ov == cv && oi < ci)) { cv = ov; ci = oi; }
      }
      bestv[kk] = cv; besti[kk] = ci;
      if (ln == ci) myp = -1.f;
    }
    float s4 = bestv[0] + bestv[1] + bestv[2] + bestv[3];
    if (ln < 4) {
      int e = besti[ln];
      int slot = atomicAdd(&counts[e], 1);
      tokl[e * T_NUM + slot] = t * 4 + ln;
      wgtl[e * T_NUM + slot] = bestv[ln] / s4;
    }
  }
}

// ---------------- tile scheduler: dense (e, mtile) list (one wave, parallel) ----------------
__global__ void sched_kernel(const int* __restrict__ counts, int* __restrict__ desc,
                             int* __restrict__ ntiles) {
  int ln = threadIdx.x;  // 64 threads, 1 block
  int nt = (ln < E_NUM) ? ((counts[ln] + 127) >> 7) : 0;
  int base = 0, tot = 0;
#pragma unroll
  for (int j = 0; j < E_NUM; ++j) {
    int v = __shfl(nt, j);
    if (j < ln) base += v;
    tot += v;
  }
  if (ln < E_NUM)
    for (int m = 0; m < nt; ++m) desc[base + m] = ln | (m << 8);
  if (ln == 0) ntiles[0] = tot;
}

// ---------------- merged gate+up GEMM (single B = wguT, N=2048) + SwiGLU epilogue --------
// 33 KB LDS, 1024 jobs. launch_bounds(256,2): R4 evidence shows the compiler emits
// 128 VGPR for this exact inner-loop shape -> HW residency 4 blocks/CU (LDS 4x33<160,
// VGPR 16 waves x 128 = 2048 pool). bound 4 forced 64 VGPR -> scratch spills (R5).
__global__ __launch_bounds__(256, 2) void gateup_kernel(
    const short* __restrict__ xbf, const short* __restrict__ wguT,
    const int* __restrict__ counts, const int* __restrict__ tokl,
    const float* __restrict__ wgtl, const int* __restrict__ desc,
    const int* __restrict__ ntiles, short* __restrict__ act) {
  __shared__ short Al[128 * BK];
  __shared__ short Bl[128 * BK];
  __shared__ int s_tok[128];
  __shared__ float s_w[128];
  int tid = threadIdx.x;
  int wv = tid >> 6, ln = tid & 63;
  int msub = (wv & 1) * 64, nsub = (wv >> 1) * 64;
  int lm = ln & 15, kq = ln >> 4;
  int total = ntiles[0] * 16;
  for (int w = blockIdx.x; w < total; w += gridDim.x) {
    int nt = w & 15;
    int d = desc[w >> 4];
    int e = d & 0xFF, m0 = (d >> 8) * 128, n0 = nt * 128;
    int cnt = counts[e];
    __syncthreads();  // protect s_tok/s_w from previous tile's epilogue
    if (tid < 128) {
      int idx = m0 + tid;
      int ok = idx < cnt;
      s_tok[tid] = ok ? tokl[e * T_NUM + idx] : 0;
      s_w[tid] = ok ? wgtl[e * T_NUM + idx] : 0.f;
    }
    __syncthreads();
    const short* ab[4]; const short* bb[4];
#pragma unroll
    for (int q = 0; q < 4; ++q) {
      int f = q * 256 + tid;
      int row = f >> 3;
      int c = (f & 7) ^ (row & 7);
      ab[q] = xbf + (size_t)(s_tok[row] >> 2) * H_DIM + c * 8;
      bb[q] = wguT + ((size_t)e * 2048 + n0 + row) * H_DIM + c * 8;
    }
    floatx4 acc[16];
    floatx4 zero = {0.f, 0.f, 0.f, 0.f};
#pragma unroll
    for (int i = 0; i < 16; ++i) acc[i] = zero;
    for (int k0 = 0; k0 < H_DIM; k0 += BK) {
      __syncthreads();
#pragma unroll
      for (int q = 0; q < 4; ++q) {
        int l8 = (q * 256 + tid) * 8;
        cp16(ab[q] + k0, Al + l8);
        cp16(bb[q] + k0, Bl + l8);
      }
      __syncthreads();
#pragma unroll
      for (int s = 0; s < 2; ++s) {
        int posA = ((s * 4 + kq) ^ (lm & 7)) * 8;
        short8 a[4], b[4];
#pragma unroll
        for (int i = 0; i < 4; ++i) a[i] = *(const short8*)(Al + (msub + i * 16 + lm) * BK + posA);
#pragma unroll
        for (int j = 0; j < 4; ++j) b[j] = *(const short8*)(Bl + (nsub + j * 16 + lm) * BK + posA);
#pragma unroll
        for (int i = 0; i < 4; ++i)
#pragma unroll
          for (int j = 0; j < 4; ++j)
            acc[i * 4 + j] = __builtin_amdgcn_mfma_f32_16x16x32_bf16(a[i], b[j], acc[i * 4 + j], 0, 0, 0);
      }
    }
    int crem = cnt - m0;
#pragma unroll
    for (int i = 0; i < 4; ++i)
#pragma unroll
      for (int p = 0; p < 2; ++p) {
        floatx4 g = acc[i * 4 + 2 * p];
        floatx4 u = acc[i * 4 + 2 * p + 1];
        int col = ((n0 + nsub) >> 1) + p * 16 + lm;  // I-column
#pragma unroll
        for (int r = 0; r < 4; ++r) {
          int rl = msub + i * 16 + kq * 4 + r;
          if (rl < crem) {
            float gv = g[r];
            float av = gv / (1.f + __expf(-gv)) * u[r] * s_w[rl];
            act[(size_t)s_tok[rl] * I_DIM + col] = f2bf(av);
          }
        }
      }
  }
}

// ---------------- down GEMM -> per-slot fp32 buffer (no atomics) ----------------
// 33 KB LDS, grid 1024; bound 2 (see gateup comment re: R5 spill regression).
__global__ __launch_bounds__(256, 2) void down_kernel(
    const short* __restrict__ act, const short* __restrict__ wdT,
    const int* __restrict__ counts, const int* __restrict__ tokl,
    const int* __restrict__ desc, const int* __restrict__ ntiles,
    float* __restrict__ outS) {
  __shared__ short Al[128 * BK];
  __shared__ short Bl[128 * BK];
  __shared__ int s_tok[128];
  int tid = threadIdx.x;
  int wv = tid >> 6, ln = tid & 63;
  int msub = (wv & 1) * 64, nsub = (wv >> 1) * 64;
  int lm = ln & 15, kq = ln >> 4;
  int total = ntiles[0] * 16;
  for (int w = blockIdx.x; w < total; w += gridDim.x) {
    int nt = w & 15;
    int d = desc[w >> 4];
    int e = d & 0xFF, m0 = (d >> 8) * 128, n0 = nt * 128;
    int cnt = counts[e];
    __syncthreads();
    if (tid < 128) {
      int idx = m0 + tid;
      s_tok[tid] = (idx < cnt) ? tokl[e * T_NUM + idx] : 0;
    }
    __syncthreads();
    const short* ab[4]; const short* bb[4];
#pragma unroll
    for (int q = 0; q < 4; ++q) {
      int f = q * 256 + tid;
      int row = f >> 3;
      int c = (f & 7) ^ (row & 7);
      ab[q] = act + (size_t)s_tok[row] * I_DIM + c * 8;
      bb[q] = wdT + ((size_t)e * H_DIM + n0 + row) * I_DIM + c * 8;
    }
    floatx4 acc[16];
    floatx4 zero = {0.f, 0.f, 0.f, 0.f};
#pragma unroll
    for (int i = 0; i < 16; ++i) acc[i] = zero;
    for (int k0 = 0; k0 < I_DIM; k0 += BK) {
      __syncthreads();
#pragma unroll
      for (int q = 0; q < 4; ++q) {
        int l8 = (q * 256 + tid) * 8;
        cp16(ab[q] + k0, Al + l8);
        cp16(bb[q] + k0, Bl + l8);
      }
      __syncthreads();
#pragma unroll
      for (int s = 0; s < 2; ++s) {
        int posA = ((s * 4 + kq) ^ (lm & 7)) * 8;
        short8 a[4], b[4];
#pragma unroll
        for (int i = 0; i < 4; ++i) a[i] = *(const short8*)(Al + (msub + i * 16 + lm) * BK + posA);
#pragma unroll
        for (int j = 0; j < 4; ++j) b[j] = *(const short8*)(Bl + (nsub + j * 16 + lm) * BK + posA);
#pragma unroll
        for (int i = 0; i < 4; ++i)
#pragma unroll
          for (int j = 0; j < 4; ++j)
            acc[i * 4 + j] = __builtin_amdgcn_mfma_f32_16x16x32_bf16(a[i], b[j], acc[i * 4 + j], 0, 0, 0);
      }
    }
    int crem = cnt - m0;
#pragma unroll
    for (int i = 0; i < 4; ++i)
#pragma unroll
      for (int j = 0; j < 4; ++j) {
        int col = n0 + nsub + j * 16 + lm;
#pragma unroll
        for (int r = 0; r < 4; ++r) {
          int rl = msub + i * 16 + kq * 4 + r;
          if (rl < crem) {
            // each (token, slot) row is written by exactly one expert tile: plain store
            outS[(size_t)s_tok[rl] * H_DIM + col] = acc[i * 4 + j][r];
          }
        }
      }
  }
}

// ---------------- slot combine: out[t][h] = sum_{s<4} outS[t*4+s][h] ----------------
__global__ __launch_bounds__(256) void reduce_kernel(
    const float* __restrict__ outS, float* __restrict__ out) {
  const int h4 = H_DIM / 4;  // 512 float4 per row
  const int n = T_NUM * h4;
  for (int i = blockIdx.x * 256 + threadIdx.x; i < n; i += gridDim.x * 256) {
    int t = i >> 9;
    int c = i & (h4 - 1);
    const float4* base = (const float4*)outS + ((size_t)t * 4) * h4 + c;
    float4 a = base[0];
    float4 b = base[h4];
    float4 d = base[2 * h4];
    float4 e = base[3 * h4];
    float4 r;
    r.x = a.x + b.x + d.x + e.x;
    r.y = a.y + b.y + d.y + e.y;
    r.z = a.z + b.z + d.z + e.z;
    r.w = a.w + b.w + d.w + e.w;
    ((float4*)out)[i] = r;
  }
}

extern "C" void kernel_launch(void* const* d_in, const int* in_sizes, int n_in,
                              void* d_out, int out_size, void* d_ws, size_t ws_size,
                              hipStream_t stream) {
  const float* x  = (const float*)d_in[0];
  const float* wr = (const float*)d_in[1];
  const float* wg = (const float*)d_in[2];
  const float* wu = (const float*)d_in[3];
  const float* wd = (const float*)d_in[4];
  float* out = (float*)d_out;

  char* ws = (char*)d_ws;
  const size_t WT_SZ = (size_t)E_NUM * I_DIM * H_DIM * 2;
  size_t off = 0;
  short* wguT = (short*)(ws + off); off += 2 * WT_SZ;  // merged, interleaved gate/up
  short* wdT = (short*)(ws + off); off += WT_SZ;
  short* xbf = (short*)(ws + off); off += (size_t)T_NUM * H_DIM * 2;
  short* act = (short*)(ws + off); off += (size_t)T_NUM * 4 * I_DIM * 2;
  int* counts = (int*)(ws + off); off += 256;
  int* tokl = (int*)(ws + off); off += (size_t)E_NUM * T_NUM * 4;
  float* wgtl = (float*)(ws + off); off += (size_t)E_NUM * T_NUM * 4;
  int* desc = (int*)(ws + off); off += 256 * 4;
  int* ntiles = (int*)(ws + off); off += 64;

  // outS (T*4 x H fp32 = 67.1 MB) aliases wguT (134 MB): dead after gateup (stream-ordered).
  float* outS = (float*)wguT;

  hipMemsetAsync(d_out, 0, (size_t)out_size * sizeof(float), stream);  // router_logits must be 0
  if (off > ws_size) return;
  hipMemsetAsync(counts, 0, 256, stream);

  dim3 blk(256);
  // wgu merge-transpose: out rows c' = 2048, cols h = 2048
  transpose_gu_kernel<<<dim3(2048 / 128, H_DIM / 128, E_NUM), blk, 0, stream>>>(wg, wu, wguT);
  // wd plain transpose: in[e][I][H] -> out[e][H][I]
  transpose_bf16_kernel<<<dim3(H_DIM / 128, I_DIM / 128, E_NUM), blk, 0, stream>>>(
      wd, wd, wdT, wdT, I_DIM, H_DIM, E_NUM);
  router_kernel<<<dim3(T_NUM), blk, 0, stream>>>(x, wr, xbf, counts, tokl, wgtl);
  sched_kernel<<<dim3(1), dim3(64), 0, stream>>>(counts, desc, ntiles);
  gateup_kernel<<<dim3(1024), blk, 0, stream>>>(xbf, wguT, counts, tokl, wgtl, desc, ntiles, act);
  down_kernel<<<dim3(1024), blk, 0, stream>>>(act, wdT, counts, tokl, desc, ntiles, outS);
  reduce_kernel<<<dim3(2048), blk, 0, stream>>>(outS, out);
}